// Round 1
// baseline (1534.362 us; speedup 1.0000x reference)
//
#include <hip/hip_runtime.h>
#include <hip/hip_bf16.h>

typedef unsigned short u16;

// ---------- bf16 helpers (manual, RNE) ----------
static __device__ __forceinline__ float b2f(u16 u) {
  return __uint_as_float(((unsigned)u) << 16);
}
static __device__ __forceinline__ u16 f2b(float f) {
  unsigned u = __float_as_uint(f);
  unsigned r = u + 0x7FFFu + ((u >> 16) & 1u);
  return (u16)(r >> 16);
}
static __device__ __forceinline__ void store_val(float* p, float v) { *p = v; }
static __device__ __forceinline__ void store_val(u16* p, float v) { *p = f2b(v); }

// Problem constants
#define CB 512
#define TT 1024
#define NH 8
#define DH 64
#define PCOLS 2048   // p stored [512][2048], col 2047 written as 0
static __constant__ float kScale = 0.044194173824159216f; // 1/sqrt(512)

// ---------- LayerNorm over channel axis ----------
// x [B,C,T] f32 -> xn [B,C,T] f32. grid (T/64, B), block 256 (64 t x 4 c-groups)
__global__ __launch_bounds__(256)
void ln_kernel(const float* __restrict__ x, const float* __restrict__ gamma,
               const float* __restrict__ beta, float* __restrict__ xn)
{
  __shared__ float sred[4][64], ssred[4][64];
  int tl = threadIdx.x & 63, cg = threadIdx.x >> 6;
  int t = blockIdx.x * 64 + tl;
  int b = blockIdx.y;
  const float* xb = x + (size_t)b * CB * TT + t;
  float s = 0.f, ss = 0.f;
  for (int c = cg * 128; c < cg * 128 + 128; ++c) {
    float v = xb[(size_t)c * TT];
    s += v; ss += v * v;
  }
  sred[cg][tl] = s; ssred[cg][tl] = ss;
  __syncthreads();
  float S = 0.f, SS = 0.f;
  #pragma unroll
  for (int g = 0; g < 4; ++g) { S += sred[g][tl]; SS += ssred[g][tl]; }
  float mean = S * (1.f / 512.f);
  float var = SS * (1.f / 512.f) - mean * mean;
  float rstd = rsqrtf(var + 1e-5f);
  float* xo = xn + (size_t)b * CB * TT + t;
  for (int c = cg * 128; c < cg * 128 + 128; ++c) {
    float v = xb[(size_t)c * TT];
    xo[(size_t)c * TT] = (v - mean) * rstd * gamma[c] + beta[c];
  }
}

// ---------- Tiled NN GEMM: out[m,n] = sum_k W[m,k]*X[k,n] + biases ----------
// W f32 [M,K] row-major (M = 64*gridDim.y, K mult of 16), X f32 [K,NX] row-major.
// out1 = acc + b0[m] + bA[m]; out2 (if DUAL) = acc + b0[m] + bB[m].
// Nout is output row stride; grid.x*64 == Nout. Cols n >= NX read as 0.
template<int DUAL, typename OutT>
__global__ __launch_bounds__(256)
void gemm_nn(const float* __restrict__ W, const float* __restrict__ X,
             int K, int NX, int Nout, long xStride, long oStride,
             const float* __restrict__ b0, const float* __restrict__ bA,
             const float* __restrict__ bB,
             OutT* __restrict__ out1, OutT* __restrict__ out2)
{
  int n0 = blockIdx.x * 64, m0 = blockIdx.y * 64, z = blockIdx.z;
  X += (size_t)z * xStride;
  const int tid = threadIdx.x;
  __shared__ float Ws[16][68];
  __shared__ float Xs[16][68];
  int tm = tid >> 4, tn = tid & 15;
  float acc[4][4] = {};
  for (int k0 = 0; k0 < K; k0 += 16) {
    __syncthreads();
    { // stage W tile [64m x 16k], transposed into Ws[k][m]
      int mm = tid >> 2, kk = (tid & 3) * 4;
      const float4 w4 = *(const float4*)&W[(size_t)(m0 + mm) * K + k0 + kk];
      Ws[kk + 0][mm] = w4.x; Ws[kk + 1][mm] = w4.y;
      Ws[kk + 2][mm] = w4.z; Ws[kk + 3][mm] = w4.w;
    }
    { // stage X tile [16k x 64n]
      int kk = tid >> 4, nn0 = (tid & 15) * 4;
      #pragma unroll
      for (int j = 0; j < 4; ++j) {
        int n = n0 + nn0 + j;
        Xs[kk][nn0 + j] = (n < NX) ? X[(size_t)(k0 + kk) * NX + n] : 0.f;
      }
    }
    __syncthreads();
    #pragma unroll
    for (int kk = 0; kk < 16; ++kk) {
      float a[4], bb[4];
      #pragma unroll
      for (int i = 0; i < 4; ++i) a[i] = Ws[kk][tm * 4 + i];
      #pragma unroll
      for (int j = 0; j < 4; ++j) bb[j] = Xs[kk][tn * 4 + j];
      #pragma unroll
      for (int i = 0; i < 4; ++i)
        #pragma unroll
        for (int j = 0; j < 4; ++j)
          acc[i][j] += a[i] * bb[j];
    }
  }
  #pragma unroll
  for (int i = 0; i < 4; ++i) {
    int m = m0 + tm * 4 + i;
    float base = b0 ? b0[m] : 0.f;
    float add1 = base + (bA ? bA[m] : 0.f);
    float add2 = base + (bB ? bB[m] : 0.f);
    #pragma unroll
    for (int j = 0; j < 4; ++j) {
      int n = n0 + tn * 4 + j;
      size_t o = (size_t)z * oStride + (size_t)m * Nout + n;
      store_val(&out1[o], acc[i][j] + add1);
      if (DUAL) store_val(&out2[o], acc[i][j] + add2);
    }
  }
}

// ---------- Pass 1: softmax denominators l[bh, qi] = sum_ki exp(score) ----------
// score[qi,ki] = (qu[:,qi].k[:,ki] + qv[:,qi].p[:,ki-qi+1023]) * kScale, masked.
// grid (T/32, B*H), block 256. Each thread: 2 qi x 4 ki micro-tile.
__global__ __launch_bounds__(256)
void stats_kernel(const u16* __restrict__ qu, const u16* __restrict__ qv,
                  const u16* __restrict__ kk, const u16* __restrict__ pp,
                  const float* __restrict__ xmask, float* __restrict__ ls)
{
  const int tid = threadIdx.x;
  int qi0 = blockIdx.x * 32;
  int bh = blockIdx.y;
  int b = bh >> 3;
  const size_t plane = (size_t)bh * DH * TT;
  const u16* quP = qu + plane;
  const u16* qvP = qv + plane;
  const u16* kP  = kk + plane;
  const u16* pP  = pp + (size_t)(bh & 7) * DH * PCOLS;
  __shared__ u16 squ[64][34], sqv[64][34], sk[64][66], sp[64][98];
  for (int e = tid; e < 64 * 32; e += 256) {
    int d = e >> 5, q = e & 31;
    squ[d][q] = quP[(size_t)d * TT + qi0 + q];
    sqv[d][q] = qvP[(size_t)d * TT + qi0 + q];
  }
  int tm = tid >> 4, tn = tid & 15;
  int qiA = qi0 + tm * 2;
  float mq[2] = { xmask[b * TT + qiA], xmask[b * TT + qiA + 1] };
  float part[2] = { 0.f, 0.f };
  const int base = tn * 4 - tm * 2 + 31;   // sp col for (i=0,j=0)
  for (int kt = 0; kt < 16; ++kt) {
    int ki0 = kt * 64;
    int j0 = ki0 - qi0 + 992;              // global p col of sp[:,0]; in [0,1952]
    __syncthreads();
    for (int e = tid; e < 64 * 64; e += 256) {
      int d = e >> 6, q = e & 63;
      sk[d][q] = kP[(size_t)d * TT + ki0 + q];
    }
    for (int e = tid; e < 64 * 96; e += 256) {
      int d = e / 96, jj = e - d * 96;
      sp[d][jj] = pP[(size_t)d * PCOLS + j0 + jj];
    }
    __syncthreads();
    float acc[2][4] = {};
    for (int d = 0; d < 64; ++d) {
      float a0 = b2f(squ[d][tm * 2]), a1 = b2f(squ[d][tm * 2 + 1]);
      float c0 = b2f(sqv[d][tm * 2]), c1 = b2f(sqv[d][tm * 2 + 1]);
      float kb[4];
      #pragma unroll
      for (int j = 0; j < 4; ++j) kb[j] = b2f(sk[d][tn * 4 + j]);
      float pb[5];
      #pragma unroll
      for (int u = 0; u < 5; ++u) pb[u] = b2f(sp[d][base - 1 + u]);
      #pragma unroll
      for (int j = 0; j < 4; ++j) {
        acc[0][j] += a0 * kb[j] + c0 * pb[j + 1]; // i=0: col = base + j
        acc[1][j] += a1 * kb[j] + c1 * pb[j];     // i=1: col = base + j - 1
      }
    }
    #pragma unroll
    for (int j = 0; j < 4; ++j) {
      float mk = xmask[b * TT + ki0 + tn * 4 + j];
      #pragma unroll
      for (int i = 0; i < 2; ++i) {
        float s = acc[i][j] * kScale;
        if (mq[i] * mk == 0.f) s = -10000.0f;
        part[i] += __expf(s);
      }
    }
  }
  #pragma unroll
  for (int i = 0; i < 2; ++i) {
    float v = part[i];
    v += __shfl_xor(v, 1); v += __shfl_xor(v, 2);
    v += __shfl_xor(v, 4); v += __shfl_xor(v, 8);
    if (tn == 0) ls[(size_t)bh * TT + qiA + i] = v;
  }
}

// ---------- Pass 2: ctx[d,t] = sum_qi v[d,qi] * exp(score[qi,t])/l[qi] ----------
// grid (T/64, B*H), block 256. Block owns 64 t cols, loops qi in tiles of 32.
__global__ __launch_bounds__(256)
void ctx_kernel(const u16* __restrict__ qu, const u16* __restrict__ qv,
                const u16* __restrict__ kk, const u16* __restrict__ vv,
                const u16* __restrict__ pp, const float* __restrict__ xmask,
                const float* __restrict__ ls, float* __restrict__ ctx)
{
  const int tid = threadIdx.x;
  int t0 = blockIdx.x * 64;
  int bh = blockIdx.y;
  int b = bh >> 3;
  const size_t plane = (size_t)bh * DH * TT;
  const u16* quP = qu + plane;
  const u16* qvP = qv + plane;
  const u16* kP  = kk + plane;
  const u16* vP  = vv + plane;
  const u16* pP  = pp + (size_t)(bh & 7) * DH * PCOLS;
  __shared__ u16 sk[64][66];
  __shared__ u16 squ[64][34], sqv[64][34], sv[64][34];
  __shared__ u16 spd[64][98];
  __shared__ float sP[32][66];
  for (int e = tid; e < 64 * 64; e += 256) {   // K tile for this t-range, once
    int d = e >> 6, q = e & 63;
    sk[d][q] = kP[(size_t)d * TT + t0 + q];
  }
  int tm = tid >> 4, tn = tid & 15;
  const int base = tn * 4 - tm * 2 + 31;
  float mt[4];
  #pragma unroll
  for (int j = 0; j < 4; ++j) mt[j] = xmask[b * TT + t0 + tn * 4 + j];
  float cacc[4][4] = {};
  for (int qt = 0; qt < 32; ++qt) {
    int qi0 = qt * 32;
    int j0 = t0 - qi0 + 992;
    __syncthreads();   // prev iter done (also orders first sk stage vs compute)
    for (int e = tid; e < 64 * 32; e += 256) {
      int d = e >> 5, q = e & 31;
      squ[d][q] = quP[(size_t)d * TT + qi0 + q];
      sqv[d][q] = qvP[(size_t)d * TT + qi0 + q];
      sv [d][q] = vP [(size_t)d * TT + qi0 + q];
    }
    for (int e = tid; e < 64 * 96; e += 256) {
      int d = e / 96, jj = e - d * 96;
      spd[d][jj] = pP[(size_t)d * PCOLS + j0 + jj];
    }
    __syncthreads();
    // scores for [qi0..qi0+32) x [t0..t0+64), micro 2x4
    float acc[2][4] = {};
    for (int d = 0; d < 64; ++d) {
      float a0 = b2f(squ[d][tm * 2]), a1 = b2f(squ[d][tm * 2 + 1]);
      float c0 = b2f(sqv[d][tm * 2]), c1 = b2f(sqv[d][tm * 2 + 1]);
      float kb[4];
      #pragma unroll
      for (int j = 0; j < 4; ++j) kb[j] = b2f(sk[d][tn * 4 + j]);
      float pb[5];
      #pragma unroll
      for (int u = 0; u < 5; ++u) pb[u] = b2f(spd[d][base - 1 + u]);
      #pragma unroll
      for (int j = 0; j < 4; ++j) {
        acc[0][j] += a0 * kb[j] + c0 * pb[j + 1];
        acc[1][j] += a1 * kb[j] + c1 * pb[j];
      }
    }
    int qiA = qi0 + tm * 2;
    float linv[2] = { 1.f / ls[(size_t)bh * TT + qiA],
                      1.f / ls[(size_t)bh * TT + qiA + 1] };
    float mq[2] = { xmask[b * TT + qiA], xmask[b * TT + qiA + 1] };
    #pragma unroll
    for (int i = 0; i < 2; ++i)
      #pragma unroll
      for (int j = 0; j < 4; ++j) {
        float s = acc[i][j] * kScale;
        if (mq[i] * mt[j] == 0.f) s = -10000.0f;
        sP[tm * 2 + i][tn * 4 + j] = __expf(s) * linv[i];
      }
    __syncthreads();
    // ctx accumulate: thread micro 4d x 4t
    for (int qq = 0; qq < 32; ++qq) {
      float vb[4], pb[4];
      #pragma unroll
      for (int i = 0; i < 4; ++i) vb[i] = b2f(sv[tm * 4 + i][qq]);
      #pragma unroll
      for (int j = 0; j < 4; ++j) pb[j] = sP[qq][tn * 4 + j];
      #pragma unroll
      for (int i = 0; i < 4; ++i)
        #pragma unroll
        for (int j = 0; j < 4; ++j)
          cacc[i][j] += vb[i] * pb[j];
    }
  }
  #pragma unroll
  for (int i = 0; i < 4; ++i)
    #pragma unroll
    for (int j = 0; j < 4; ++j)
      ctx[((size_t)bh * DH + tm * 4 + i) * TT + t0 + tn * 4 + j] = cacc[i][j];
}

// ---------- launch ----------
extern "C" void kernel_launch(void* const* d_in, const int* in_sizes, int n_in,
                              void* d_out, int out_size, void* d_ws, size_t ws_size,
                              hipStream_t stream)
{
  (void)in_sizes; (void)n_in; (void)out_size;
  const float* x     = (const float*)d_in[0];
  const float* pe    = (const float*)d_in[1];
  const float* xm    = (const float*)d_in[2];
  const float* gamma = (const float*)d_in[3];
  const float* beta  = (const float*)d_in[4];
  const float* Wq    = (const float*)d_in[5];
  const float* bq    = (const float*)d_in[6];
  const float* Wk    = (const float*)d_in[7];
  const float* bk    = (const float*)d_in[8];
  const float* Wv    = (const float*)d_in[9];
  const float* bv    = (const float*)d_in[10];
  const float* Wp    = (const float*)d_in[11];
  const float* ub    = (const float*)d_in[12];
  const float* vb    = (const float*)d_in[13];
  const float* Wo    = (const float*)d_in[14];
  const float* bo    = (const float*)d_in[15];

  // workspace layout (bytes)
  char* ws = (char*)d_ws;
  float* xn  = (float*)(ws + 0);          // 2,097,152 f32
  u16*  quB  = (u16*) (ws + 8388608);     // 2,097,152 bf16
  u16*  qvB  = (u16*) (ws + 12582912);
  u16*  kB   = (u16*) (ws + 16777216);
  u16*  vB   = (u16*) (ws + 20971520);
  u16*  pB   = (u16*) (ws + 25165824);    // 512*2048 bf16
  float* lsB = (float*)(ws + 27262976);   // 32768 f32
  float* ctx = (float*)(ws + 27394048);   // 2,097,152 f32
  if (ws_size < 35782656) return;         // fail loudly (poison stays in d_out)

  const long BS = (long)CB * TT;          // per-batch element stride
  dim3 blk(256);

  ln_kernel<<<dim3(TT / 64, 4), blk, 0, stream>>>(x, gamma, beta, xn);
  // q -> qu (= q+bq+u), qv (= q+bq+v); k, v plain
  gemm_nn<1, u16><<<dim3(16, 8, 4), blk, 0, stream>>>(Wq, xn, CB, TT, TT, BS, BS, bq, ub, vb, quB, qvB);
  gemm_nn<0, u16><<<dim3(16, 8, 4), blk, 0, stream>>>(Wk, xn, CB, TT, TT, BS, BS, bk, nullptr, nullptr, kB, nullptr);
  gemm_nn<0, u16><<<dim3(16, 8, 4), blk, 0, stream>>>(Wv, xn, CB, TT, TT, BS, BS, bv, nullptr, nullptr, vB, nullptr);
  // p = Wp @ pos_emb, stored [512][2048], col 2047 = 0
  gemm_nn<0, u16><<<dim3(32, 8, 1), blk, 0, stream>>>(Wp, pe, CB, 2047, PCOLS, 0, 0, nullptr, nullptr, nullptr, pB, nullptr);
  stats_kernel<<<dim3(32, 32), blk, 0, stream>>>(quB, qvB, kB, pB, xm, lsB);
  ctx_kernel<<<dim3(16, 32), blk, 0, stream>>>(quB, qvB, kB, vB, pB, xm, lsB, ctx);
  gemm_nn<0, float><<<dim3(16, 8, 4), blk, 0, stream>>>(Wo, ctx, CB, TT, TT, BS, BS, bo, nullptr, nullptr, (float*)d_out, nullptr);
}

// Round 2
// 385.911 us; speedup vs baseline: 3.9759x; 3.9759x over previous
//
#include <hip/hip_runtime.h>
#include <hip/hip_bf16.h>

typedef unsigned short u16;
typedef __bf16 bf16_t;
typedef bf16_t bf16x8 __attribute__((ext_vector_type(8)));
typedef float f32x4 __attribute__((ext_vector_type(4)));

#define MFMA16(A,B,C) __builtin_amdgcn_mfma_f32_16x16x32_bf16(A,B,C,0,0,0)

// Problem constants
#define CB 512
#define TT 1024
#define NH 8
#define DH 64
static __constant__ float kScale = 0.044194173824159216f; // 1/sqrt(512)

static __device__ __forceinline__ u16 f2b(float f) {
  unsigned u = __float_as_uint(f);
  unsigned r = u + 0x7FFFu + ((u >> 16) & 1u);
  return (u16)(r >> 16);
}
static __device__ __forceinline__ void store_val(float* p, float v) { *p = v; }
static __device__ __forceinline__ void store_val(u16* p, float v) { *p = f2b(v); }
static __device__ __forceinline__ bf16x8 ldb8(const u16* p) {
  return *reinterpret_cast<const bf16x8*>(p);
}

// ---------- LayerNorm over channel axis ----------
__global__ __launch_bounds__(256)
void ln_kernel(const float* __restrict__ x, const float* __restrict__ gamma,
               const float* __restrict__ beta, float* __restrict__ xn)
{
  __shared__ float sred[4][64], ssred[4][64];
  int tl = threadIdx.x & 63, cg = threadIdx.x >> 6;
  int t = blockIdx.x * 64 + tl;
  int b = blockIdx.y;
  const float* xb = x + (size_t)b * CB * TT + t;
  float s = 0.f, ss = 0.f;
  for (int c = cg * 128; c < cg * 128 + 128; ++c) {
    float v = xb[(size_t)c * TT];
    s += v; ss += v * v;
  }
  sred[cg][tl] = s; ssred[cg][tl] = ss;
  __syncthreads();
  float S = 0.f, SS = 0.f;
  #pragma unroll
  for (int g = 0; g < 4; ++g) { S += sred[g][tl]; SS += ssred[g][tl]; }
  float mean = S * (1.f / 512.f);
  float var = SS * (1.f / 512.f) - mean * mean;
  float rstd = rsqrtf(var + 1e-5f);
  float* xo = xn + (size_t)b * CB * TT + t;
  for (int c = cg * 128; c < cg * 128 + 128; ++c) {
    float v = xb[(size_t)c * TT];
    xo[(size_t)c * TT] = (v - mean) * rstd * gamma[c] + beta[c];
  }
}

// ---------- Tiled NN GEMM: out[m,n] = sum_k W[m,k]*X[k,n] + biases ----------
// OMODE 0: out[z*oStride + m*Nout + n] (OutT f32 or u16)
// OMODE 1: per-head transpose, out[z*oStride + ((m>>6)*Nout + n)*64 + (m&63)], u16
// OMODE 2: same as 1 with z folding absent (used for p), u16
template<int DUAL, int OMODE, typename OutT>
__global__ __launch_bounds__(256)
void gemm_nn(const float* __restrict__ W, const float* __restrict__ X,
             int K, int NX, int Nout, long xStride, long oStride,
             const float* __restrict__ b0, const float* __restrict__ bA,
             const float* __restrict__ bB,
             OutT* __restrict__ out1, OutT* __restrict__ out2)
{
  int n0 = blockIdx.x * 64, m0 = blockIdx.y * 64, z = blockIdx.z;
  X += (size_t)z * xStride;
  const int tid = threadIdx.x;
  __shared__ float Ws[16][68];
  __shared__ float Xs[16][68];
  int tm = tid >> 4, tn = tid & 15;
  float acc[4][4] = {};
  for (int k0 = 0; k0 < K; k0 += 16) {
    __syncthreads();
    {
      int mm = tid >> 2, kk = (tid & 3) * 4;
      const float4 w4 = *(const float4*)&W[(size_t)(m0 + mm) * K + k0 + kk];
      Ws[kk + 0][mm] = w4.x; Ws[kk + 1][mm] = w4.y;
      Ws[kk + 2][mm] = w4.z; Ws[kk + 3][mm] = w4.w;
    }
    {
      int kk = tid >> 4, nn0 = (tid & 15) * 4;
      #pragma unroll
      for (int j = 0; j < 4; ++j) {
        int n = n0 + nn0 + j;
        Xs[kk][nn0 + j] = (n < NX) ? X[(size_t)(k0 + kk) * NX + n] : 0.f;
      }
    }
    __syncthreads();
    #pragma unroll
    for (int kk = 0; kk < 16; ++kk) {
      float a[4], bb[4];
      #pragma unroll
      for (int i = 0; i < 4; ++i) a[i] = Ws[kk][tm * 4 + i];
      #pragma unroll
      for (int j = 0; j < 4; ++j) bb[j] = Xs[kk][tn * 4 + j];
      #pragma unroll
      for (int i = 0; i < 4; ++i)
        #pragma unroll
        for (int j = 0; j < 4; ++j)
          acc[i][j] += a[i] * bb[j];
    }
  }
  float add1v[4], add2v[4];
  #pragma unroll
  for (int i = 0; i < 4; ++i) {
    int m = m0 + tm * 4 + i;
    float base = b0 ? b0[m] : 0.f;
    add1v[i] = base + (bA ? bA[m] : 0.f);
    add2v[i] = base + (bB ? bB[m] : 0.f);
  }
  if constexpr (OMODE == 0) {
    #pragma unroll
    for (int i = 0; i < 4; ++i) {
      int m = m0 + tm * 4 + i;
      #pragma unroll
      for (int j = 0; j < 4; ++j) {
        int n = n0 + tn * 4 + j;
        size_t o = (size_t)z * oStride + (size_t)m * Nout + n;
        store_val(&out1[o], acc[i][j] + add1v[i]);
        if (DUAL) store_val(&out2[o], acc[i][j] + add2v[i]);
      }
    }
  } else {
    #pragma unroll
    for (int j = 0; j < 4; ++j) {
      int n = n0 + tn * 4 + j;
      size_t o = (size_t)z * oStride + ((size_t)(m0 >> 6) * Nout + n) * 64 + tm * 4;
      ushort4 s1;
      s1.x = f2b(acc[0][j] + add1v[0]); s1.y = f2b(acc[1][j] + add1v[1]);
      s1.z = f2b(acc[2][j] + add1v[2]); s1.w = f2b(acc[3][j] + add1v[3]);
      *reinterpret_cast<ushort4*>((u16*)out1 + o) = s1;
      if (DUAL) {
        ushort4 s2;
        s2.x = f2b(acc[0][j] + add2v[0]); s2.y = f2b(acc[1][j] + add2v[1]);
        s2.z = f2b(acc[2][j] + add2v[2]); s2.w = f2b(acc[3][j] + add2v[3]);
        *reinterpret_cast<ushort4*>((u16*)out2 + o) = s2;
      }
    }
  }
}

// ---------- Pass 1 (MFMA): l[bh,qi] = sum_ki exp(score) ----------
// qu/qv/k in [bh][t][dh] bf16, p in [h][2048][dh] bf16 (col 2047 = 0).
// grid (32, 32): blockIdx.x = qi-tile of 32, blockIdx.y = bh. 4 waves split ki.
__global__ __launch_bounds__(256)
void stats_mfma(const u16* __restrict__ qu, const u16* __restrict__ qv,
                const u16* __restrict__ kk_, const u16* __restrict__ pp,
                const float* __restrict__ xmask, float* __restrict__ ls)
{
  const int tid = threadIdx.x;
  const int w = tid >> 6, lane = tid & 63;
  const int ln16 = lane & 15, kg = lane >> 4;
  const int qi0 = blockIdx.x * 32;
  const int bh = blockIdx.y, b = bh >> 3, h = bh & 7;
  const u16* quP = qu + (size_t)bh * TT * DH;
  const u16* qvP = qv + (size_t)bh * TT * DH;
  const u16* kP  = kk_ + (size_t)bh * TT * DH;
  const u16* pP  = pp + (size_t)h * 2048 * DH;

  __shared__ float G[4][32][98];   // per-wave pos band [qi 32][u 96], W=98 pad
  __shared__ float red[4][32];

  bf16x8 qa[2][2], va[2][2];
  #pragma unroll
  for (int mt = 0; mt < 2; ++mt)
    #pragma unroll
    for (int kc = 0; kc < 2; ++kc) {
      const size_t o = (size_t)(qi0 + mt * 16 + ln16) * DH + kc * 32 + kg * 8;
      qa[mt][kc] = ldb8(&quP[o]);
      va[mt][kc] = ldb8(&qvP[o]);
    }
  float aq[2][4];
  #pragma unroll
  for (int mt = 0; mt < 2; ++mt)
    #pragma unroll
    for (int jr = 0; jr < 4; ++jr)
      aq[mt][jr] = (xmask[b * TT + qi0 + mt * 16 + kg * 4 + jr] - 1.f) * 10000.f;

  float rs[2][4] = {};
  for (int c = 0; c < 4; ++c) {
    const int ki0 = (c * 4 + w) * 64;
    const int j0 = ki0 - qi0 + 992;          // p band start, in [0,1952]
    // G = qv^T * p_band : M=32, N=96, K=64
    #pragma unroll
    for (int nt = 0; nt < 6; ++nt) {
      const size_t po = (size_t)(j0 + nt * 16 + ln16) * DH + kg * 8;
      bf16x8 pb0 = ldb8(&pP[po]);
      bf16x8 pb1 = ldb8(&pP[po + 32]);
      #pragma unroll
      for (int mt = 0; mt < 2; ++mt) {
        f32x4 g = {0.f, 0.f, 0.f, 0.f};
        g = MFMA16(va[mt][0], pb0, g);
        g = MFMA16(va[mt][1], pb1, g);
        #pragma unroll
        for (int jr = 0; jr < 4; ++jr)
          G[w][mt * 16 + kg * 4 + jr][nt * 16 + ln16] = g[jr];
      }
    }
    // content + gather + exp
    #pragma unroll
    for (int nt = 0; nt < 4; ++nt) {
      const size_t ko = (size_t)(ki0 + nt * 16 + ln16) * DH + kg * 8;
      bf16x8 kb0 = ldb8(&kP[ko]);
      bf16x8 kb1 = ldb8(&kP[ko + 32]);
      const float ak = (xmask[b * TT + ki0 + nt * 16 + ln16] - 1.f) * 10000.f;
      #pragma unroll
      for (int mt = 0; mt < 2; ++mt) {
        f32x4 dd = {0.f, 0.f, 0.f, 0.f};
        dd = MFMA16(qa[mt][0], kb0, dd);
        dd = MFMA16(qa[mt][1], kb1, dd);
        #pragma unroll
        for (int jr = 0; jr < 4; ++jr) {
          const int qrow = mt * 16 + kg * 4 + jr;
          const int u = nt * 16 + ln16 - qrow + 31;   // (ki-ki0)-(qi-qi0)+31
          const float s = (dd[jr] + G[w][qrow][u]) * kScale + aq[mt][jr] + ak;
          rs[mt][jr] += __expf(s);
        }
      }
    }
  }
  #pragma unroll
  for (int mt = 0; mt < 2; ++mt)
    #pragma unroll
    for (int jr = 0; jr < 4; ++jr) {
      float v = rs[mt][jr];
      v += __shfl_xor(v, 1); v += __shfl_xor(v, 2);
      v += __shfl_xor(v, 4); v += __shfl_xor(v, 8);
      rs[mt][jr] = v;
    }
  if (ln16 == 0) {
    #pragma unroll
    for (int mt = 0; mt < 2; ++mt)
      #pragma unroll
      for (int jr = 0; jr < 4; ++jr)
        red[w][mt * 16 + kg * 4 + jr] = rs[mt][jr];
  }
  __syncthreads();
  if (tid < 32)
    ls[(size_t)bh * TT + qi0 + tid] = red[0][tid] + red[1][tid] + red[2][tid] + red[3][tid];
}

// ---------- Pass 2 (MFMA): ctx[d,t] = sum_qi v[d,qi] * exp(score[qi,t])/l[qi] ----------
// grid (16, 32): blockIdx.x = t-tile of 64; 4 waves: each wave owns 16 qi rows
// of the score chunk and 16 d rows of the PV output.
__global__ __launch_bounds__(256)
void ctx_mfma(const u16* __restrict__ qu, const u16* __restrict__ qv,
              const u16* __restrict__ kk_, const u16* __restrict__ vv,
              const u16* __restrict__ pp, const float* __restrict__ xmask,
              const float* __restrict__ ls, float* __restrict__ ctx)
{
  const int tid = threadIdx.x;
  const int w = tid >> 6, lane = tid & 63;
  const int ln16 = lane & 15, kg = lane >> 4;
  const int t0 = blockIdx.x * 64;
  const int bh = blockIdx.y, b = bh >> 3, h = bh & 7;
  const u16* quP = qu + (size_t)bh * TT * DH;
  const u16* qvP = qv + (size_t)bh * TT * DH;
  const u16* kP  = kk_ + (size_t)bh * TT * DH;
  const u16* vP  = vv + (size_t)bh * DH * TT;    // [d][t]
  const u16* pP  = pp + (size_t)h * 2048 * DH;
  const float* lsP = ls + (size_t)bh * TT;

  __shared__ float G[4][16][83];                 // per-wave pos band [qi 16][u 80]
  __shared__ __align__(16) u16 P[64][72];        // P[t][qi_local], bf16

  bf16x8 ka[4][2];                               // B frags for content (fixed t-tile)
  #pragma unroll
  for (int nt = 0; nt < 4; ++nt)
    #pragma unroll
    for (int kc = 0; kc < 2; ++kc)
      ka[nt][kc] = ldb8(&kP[(size_t)(t0 + nt * 16 + ln16) * DH + kc * 32 + kg * 8]);
  float at4[4];
  #pragma unroll
  for (int nt = 0; nt < 4; ++nt)
    at4[nt] = (xmask[b * TT + t0 + nt * 16 + ln16] - 1.f) * 10000.f;

  f32x4 cacc[4] = {};
  for (int qc = 0; qc < 16; ++qc) {
    const int qw = qc * 64 + w * 16;             // this wave's qi rows
    const int j0 = t0 - qw + 1008;               // p band start, in [0,1968]
    const size_t qo = (size_t)(qw + ln16) * DH + kg * 8;
    bf16x8 qa0 = ldb8(&quP[qo]), qa1 = ldb8(&quP[qo + 32]);
    bf16x8 va0 = ldb8(&qvP[qo]), va1 = ldb8(&qvP[qo + 32]);
    #pragma unroll
    for (int nt = 0; nt < 5; ++nt) {
      const size_t po = (size_t)(j0 + nt * 16 + ln16) * DH + kg * 8;
      bf16x8 pb0 = ldb8(&pP[po]), pb1 = ldb8(&pP[po + 32]);
      f32x4 g = {0.f, 0.f, 0.f, 0.f};
      g = MFMA16(va0, pb0, g);
      g = MFMA16(va1, pb1, g);
      #pragma unroll
      for (int jr = 0; jr < 4; ++jr)
        G[w][kg * 4 + jr][nt * 16 + ln16] = g[jr];
    }
    float linv[4], aqv[4];
    #pragma unroll
    for (int jr = 0; jr < 4; ++jr) {
      const int qi = qw + kg * 4 + jr;
      linv[jr] = 1.f / lsP[qi];
      aqv[jr] = (xmask[b * TT + qi] - 1.f) * 10000.f;
    }
    __syncthreads();                             // prev chunk's PV reads done
    #pragma unroll
    for (int nt = 0; nt < 4; ++nt) {
      f32x4 dd = {0.f, 0.f, 0.f, 0.f};
      dd = MFMA16(qa0, ka[nt][0], dd);
      dd = MFMA16(qa1, ka[nt][1], dd);
      unsigned lo = 0, hi = 0;
      #pragma unroll
      for (int jr = 0; jr < 4; ++jr) {
        const int qrow = kg * 4 + jr;
        const int u = nt * 16 + ln16 - qrow + 15;
        const float s = (dd[jr] + G[w][qrow][u]) * kScale + aqv[jr] + at4[nt];
        const float e = __expf(s) * linv[jr];
        const unsigned bb = f2b(e);
        if (jr == 0) lo = bb; else if (jr == 1) lo |= bb << 16;
        else if (jr == 2) hi = bb; else hi |= bb << 16;
      }
      *reinterpret_cast<uint2*>(&P[nt * 16 + ln16][w * 16 + kg * 4]) = make_uint2(lo, hi);
    }
    __syncthreads();                             // P complete
    const size_t vo = (size_t)(w * 16 + ln16) * TT + qc * 64 + kg * 8;
    bf16x8 vf0 = ldb8(&vP[vo]), vf1 = ldb8(&vP[vo + 32]);
    #pragma unroll
    for (int nt = 0; nt < 4; ++nt) {
      bf16x8 pb0 = *reinterpret_cast<const bf16x8*>(&P[nt * 16 + ln16][kg * 8]);
      bf16x8 pb1 = *reinterpret_cast<const bf16x8*>(&P[nt * 16 + ln16][32 + kg * 8]);
      cacc[nt] = MFMA16(vf0, pb0, cacc[nt]);
      cacc[nt] = MFMA16(vf1, pb1, cacc[nt]);
    }
  }
  #pragma unroll
  for (int nt = 0; nt < 4; ++nt)
    #pragma unroll
    for (int jr = 0; jr < 4; ++jr)
      ctx[((size_t)bh * DH + w * 16 + kg * 4 + jr) * TT + t0 + nt * 16 + ln16] = cacc[nt][jr];
}

// ---------- launch ----------
extern "C" void kernel_launch(void* const* d_in, const int* in_sizes, int n_in,
                              void* d_out, int out_size, void* d_ws, size_t ws_size,
                              hipStream_t stream)
{
  (void)in_sizes; (void)n_in; (void)out_size;
  const float* x     = (const float*)d_in[0];
  const float* pe    = (const float*)d_in[1];
  const float* xm    = (const float*)d_in[2];
  const float* gamma = (const float*)d_in[3];
  const float* beta  = (const float*)d_in[4];
  const float* Wq    = (const float*)d_in[5];
  const float* bq    = (const float*)d_in[6];
  const float* Wk    = (const float*)d_in[7];
  const float* bk    = (const float*)d_in[8];
  const float* Wv    = (const float*)d_in[9];
  const float* bv    = (const float*)d_in[10];
  const float* Wp    = (const float*)d_in[11];
  const float* ub    = (const float*)d_in[12];
  const float* vb    = (const float*)d_in[13];
  const float* Wo    = (const float*)d_in[14];
  const float* bo    = (const float*)d_in[15];

  // workspace layout (bytes)
  char* ws = (char*)d_ws;
  float* xn  = (float*)(ws + 0);          // [4][512][1024] f32
  u16*  quB  = (u16*) (ws + 8388608);     // [32][1024][64] bf16  (q+bq+u, t-major)
  u16*  qvB  = (u16*) (ws + 12582912);    // [32][1024][64] bf16  (q+bq+v)
  u16*  kB   = (u16*) (ws + 16777216);    // [32][1024][64] bf16  (t-major)
  u16*  vB   = (u16*) (ws + 20971520);    // [32][64][1024] bf16  (d-major)
  u16*  pB   = (u16*) (ws + 25165824);    // [8][2048][64] bf16, col 2047 = 0
  float* lsB = (float*)(ws + 27262976);   // [32][1024] f32
  float* ctx = (float*)(ws + 27394048);   // [32][64][1024] f32
  if (ws_size < 35782656) return;

  const long BS = (long)CB * TT;
  dim3 blk(256);

  ln_kernel<<<dim3(TT / 64, 4), blk, 0, stream>>>(x, gamma, beta, xn);
  gemm_nn<1, 1, u16><<<dim3(16, 8, 4), blk, 0, stream>>>(Wq, xn, CB, TT, TT, BS, BS, bq, ub, vb, quB, qvB);
  gemm_nn<0, 1, u16><<<dim3(16, 8, 4), blk, 0, stream>>>(Wk, xn, CB, TT, TT, BS, BS, bk, nullptr, nullptr, kB, nullptr);
  gemm_nn<0, 0, u16><<<dim3(16, 8, 4), blk, 0, stream>>>(Wv, xn, CB, TT, TT, BS, BS, bv, nullptr, nullptr, vB, nullptr);
  gemm_nn<0, 2, u16><<<dim3(32, 8, 1), blk, 0, stream>>>(Wp, pe, CB, 2047, 2048, 0, 0, nullptr, nullptr, nullptr, pB, nullptr);
  stats_mfma<<<dim3(32, 32), blk, 0, stream>>>(quB, qvB, kB, pB, xm, lsB);
  ctx_mfma<<<dim3(16, 32), blk, 0, stream>>>(quB, qvB, kB, vB, pB, xm, lsB, ctx);
  gemm_nn<0, 0, float><<<dim3(16, 8, 4), blk, 0, stream>>>(Wo, ctx, CB, TT, TT, BS, BS, bo, nullptr, nullptr, (float*)d_out, nullptr);
}

// Round 3
// 276.961 us; speedup vs baseline: 5.5400x; 1.3934x over previous
//
#include <hip/hip_runtime.h>
#include <hip/hip_bf16.h>

typedef unsigned short u16;
typedef __bf16 bf16_t;
typedef bf16_t bf16x8 __attribute__((ext_vector_type(8)));
typedef float f32x4 __attribute__((ext_vector_type(4)));
typedef u16 u16x8 __attribute__((ext_vector_type(8)));

#define MFMA16(A,B,C) __builtin_amdgcn_mfma_f32_16x16x32_bf16(A,B,C,0,0,0)

#define CB 512
#define TT 1024
#define NH 8
#define DH 64
static __constant__ float kScale = 0.044194173824159216f; // 1/sqrt(512)

static __device__ __forceinline__ u16 f2b(float f) {
  unsigned u = __float_as_uint(f);
  unsigned r = u + 0x7FFFu + ((u >> 16) & 1u);
  return (u16)(r >> 16);
}
static __device__ __forceinline__ bf16x8 ldb8(const u16* p) {
  return *reinterpret_cast<const bf16x8*>(p);
}

// ---------- fp32 -> bf16 elementwise (8/thread) ----------
__global__ __launch_bounds__(256)
void convert_bf16(const float* __restrict__ src, u16* __restrict__ dst, int n8)
{
  int i = blockIdx.x * 256 + threadIdx.x;
  if (i >= n8) return;
  const float4 a = ((const float4*)src)[i * 2 + 0];
  const float4 b = ((const float4*)src)[i * 2 + 1];
  u16x8 o;
  o[0] = f2b(a.x); o[1] = f2b(a.y); o[2] = f2b(a.z); o[3] = f2b(a.w);
  o[4] = f2b(b.x); o[5] = f2b(b.y); o[6] = f2b(b.z); o[7] = f2b(b.w);
  *(u16x8*)(dst + (size_t)i * 8) = o;
}

// ---------- Wo [512][512] fp32 -> [Wo|Wo] [512][1024] bf16 ----------
__global__ __launch_bounds__(256)
void convert_wo2(const float* __restrict__ src, u16* __restrict__ dst)
{
  int i = blockIdx.x * 256 + threadIdx.x;     // 65536 groups of 8
  int m = i >> 7;
  int k0 = (i & 127) * 8;
  const float* s = src + (size_t)m * 512 + (k0 & 511);
  const float4 a = *(const float4*)s;
  const float4 b = *(const float4*)(s + 4);
  u16x8 o;
  o[0] = f2b(a.x); o[1] = f2b(a.y); o[2] = f2b(a.z); o[3] = f2b(a.w);
  o[4] = f2b(b.x); o[5] = f2b(b.y); o[6] = f2b(b.z); o[7] = f2b(b.w);
  *(u16x8*)(dst + (size_t)m * 1024 + k0) = o;
}

// ---------- pos_emb [512][2047] fp32 -> posT [2048][512] bf16 (row 2047 = 0) ----------
__global__ __launch_bounds__(256)
void transpose_pe(const float* __restrict__ pe, u16* __restrict__ posT)
{
  __shared__ float tile[64][65];
  int j0 = blockIdx.x * 64, c0 = blockIdx.y * 64;
  for (int e = threadIdx.x; e < 4096; e += 256) {
    int cc = e >> 6, jj = e & 63;
    int j = j0 + jj;
    tile[jj][cc] = (j < 2047) ? pe[(size_t)(c0 + cc) * 2047 + j] : 0.f;
  }
  __syncthreads();
  for (int e = threadIdx.x; e < 4096; e += 256) {
    int jj = e >> 6, cc = e & 63;
    posT[(size_t)(j0 + jj) * 512 + c0 + cc] = f2b(tile[jj][cc]);
  }
}

// ---------- LayerNorm over channel axis; emits xnT [b][t][c] bf16 ----------
__global__ __launch_bounds__(256)
void ln_kernel(const float* __restrict__ x, const float* __restrict__ gamma,
               const float* __restrict__ beta, u16* __restrict__ xnT)
{
  __shared__ float sred[8][33], ssred[8][33];
  int tl = threadIdx.x & 31, cg = threadIdx.x >> 5;
  int t = blockIdx.x * 32 + tl;
  int b = blockIdx.y;
  const float* xb = x + (size_t)b * CB * TT + t;
  float s = 0.f, ss = 0.f;
  for (int c = cg * 64; c < cg * 64 + 64; ++c) {
    float v = xb[(size_t)c * TT];
    s += v; ss += v * v;
  }
  sred[cg][tl] = s; ssred[cg][tl] = ss;
  __syncthreads();
  float S = 0.f, SS = 0.f;
  #pragma unroll
  for (int g = 0; g < 8; ++g) { S += sred[g][tl]; SS += ssred[g][tl]; }
  float mean = S * (1.f / 512.f);
  float var = SS * (1.f / 512.f) - mean * mean;
  float rstd = rsqrtf(var + 1e-5f);
  u16* orow = xnT + ((size_t)b * TT + t) * CB;
  for (int c8 = 0; c8 < 8; ++c8) {
    int c = cg * 64 + c8 * 8;
    u16x8 o;
    #pragma unroll
    for (int j = 0; j < 8; ++j) {
      float v = xb[(size_t)(c + j) * TT];
      o[j] = f2b((v - mean) * rstd * gamma[c + j] + beta[c + j]);
    }
    *(u16x8*)(orow + c) = o;
  }
}

// ---------- MFMA GEMM: out[m,n] = sum_k W[m,k]*XT[n,k] + bias(m) ----------
// W bf16 [M][K] row-major, XT bf16 [N][K] row-major (per z: + z*xStride elems).
// grid (N/64, M/32, Z), block 256 = 4 waves; wave: msub=(w&1)*16, nsub=(w>>1)*32.
// OMODE 0: f32 out[z*oStride + m*Nout + n]
// OMODE 1: u16 per-head transpose out[z*oStride + ((m>>6)*Nout + n)*64 + (m&63)]
// OMODE 2: u16 out[z*oStride + m*Nout + n]
template<int K, int OMODE, int DUAL>
__global__ __launch_bounds__(256)
void gemm_mfma(const u16* __restrict__ W, const u16* __restrict__ XT,
               long xStride, long oStride, int Nout,
               const float* __restrict__ b0, const float* __restrict__ bA,
               const float* __restrict__ bB,
               void* __restrict__ out1v, void* __restrict__ out2v)
{
  const int tid = threadIdx.x, w = tid >> 6, lane = tid & 63;
  const int ln16 = lane & 15, kg = lane >> 4;
  const int n0 = blockIdx.x * 64 + (w >> 1) * 32;
  const int m0 = blockIdx.y * 32 + (w & 1) * 16;
  const int z = blockIdx.z;
  const u16* Arow = W + (size_t)(m0 + ln16) * K + kg * 8;
  const u16* B0row = XT + (size_t)z * xStride + (size_t)(n0 + ln16) * K + kg * 8;
  const u16* B1row = B0row + (size_t)16 * K;
  f32x4 acc0 = {0.f, 0.f, 0.f, 0.f}, acc1 = {0.f, 0.f, 0.f, 0.f};
  #pragma unroll 4
  for (int ks = 0; ks < K / 32; ++ks) {
    bf16x8 a = ldb8(Arow + ks * 32);
    bf16x8 bb0 = ldb8(B0row + ks * 32);
    bf16x8 bb1 = ldb8(B1row + ks * 32);
    acc0 = MFMA16(a, bb0, acc0);
    acc1 = MFMA16(a, bb1, acc1);
  }
  float add1[4], add2[4];
  #pragma unroll
  for (int jr = 0; jr < 4; ++jr) {
    int m = m0 + kg * 4 + jr;
    float base = b0 ? b0[m] : 0.f;
    add1[jr] = base + (bA ? bA[m] : 0.f);
    add2[jr] = base + (bB ? bB[m] : 0.f);
  }
  #pragma unroll
  for (int nt = 0; nt < 2; ++nt) {
    const f32x4 acc = nt ? acc1 : acc0;
    const int n = n0 + nt * 16 + ln16;
    if constexpr (OMODE == 0) {
      float* out1 = (float*)out1v;
      #pragma unroll
      for (int jr = 0; jr < 4; ++jr)
        out1[(size_t)z * oStride + (size_t)(m0 + kg * 4 + jr) * Nout + n] = acc[jr] + add1[jr];
    } else if constexpr (OMODE == 2) {
      u16* out1 = (u16*)out1v;
      #pragma unroll
      for (int jr = 0; jr < 4; ++jr)
        out1[(size_t)z * oStride + (size_t)(m0 + kg * 4 + jr) * Nout + n] = f2b(acc[jr] + add1[jr]);
    } else {
      const size_t o = (size_t)z * oStride +
                       ((size_t)(m0 >> 6) * Nout + n) * 64 + (m0 & 63) + kg * 4;
      ushort4 s1;
      s1.x = f2b(acc[0] + add1[0]); s1.y = f2b(acc[1] + add1[1]);
      s1.z = f2b(acc[2] + add1[2]); s1.w = f2b(acc[3] + add1[3]);
      *reinterpret_cast<ushort4*>((u16*)out1v + o) = s1;
      if constexpr (DUAL) {
        ushort4 s2;
        s2.x = f2b(acc[0] + add2[0]); s2.y = f2b(acc[1] + add2[1]);
        s2.z = f2b(acc[2] + add2[2]); s2.w = f2b(acc[3] + add2[3]);
        *reinterpret_cast<ushort4*>((u16*)out2v + o) = s2;
      }
    }
  }
}

// ---------- Pass 1 (MFMA): l[bh,qi] = sum_ki exp(score) ----------
// flat grid 1024; XCD-aware decode: bh % 8 == blockid % 8.
__global__ __launch_bounds__(256)
void stats_mfma(const u16* __restrict__ qu, const u16* __restrict__ qv,
                const u16* __restrict__ kk_, const u16* __restrict__ pp,
                const float* __restrict__ xmask, float* __restrict__ ls)
{
  const int tid = threadIdx.x;
  const int w = tid >> 6, lane = tid & 63;
  const int ln16 = lane & 15, kg = lane >> 4;
  const int bid = blockIdx.x;
  const int bh = (bid & 7) + 8 * ((bid >> 3) & 3);
  const int qi0 = (bid >> 5) * 32;
  const int b = bh >> 3, h = bh & 7;
  const u16* quP = qu + (size_t)bh * TT * DH;
  const u16* qvP = qv + (size_t)bh * TT * DH;
  const u16* kP  = kk_ + (size_t)bh * TT * DH;
  const u16* pP  = pp + (size_t)h * 2048 * DH;

  __shared__ float G[4][32][98];
  __shared__ float red[4][32];

  bf16x8 qa[2][2], va[2][2];
  #pragma unroll
  for (int mt = 0; mt < 2; ++mt)
    #pragma unroll
    for (int kc = 0; kc < 2; ++kc) {
      const size_t o = (size_t)(qi0 + mt * 16 + ln16) * DH + kc * 32 + kg * 8;
      qa[mt][kc] = ldb8(&quP[o]);
      va[mt][kc] = ldb8(&qvP[o]);
    }
  float aq[2][4];
  #pragma unroll
  for (int mt = 0; mt < 2; ++mt)
    #pragma unroll
    for (int jr = 0; jr < 4; ++jr)
      aq[mt][jr] = (xmask[b * TT + qi0 + mt * 16 + kg * 4 + jr] - 1.f) * 10000.f;

  float rs[2][4] = {};
  for (int c = 0; c < 4; ++c) {
    const int ki0 = (c * 4 + w) * 64;
    const int j0 = ki0 - qi0 + 992;
    #pragma unroll
    for (int nt = 0; nt < 6; ++nt) {
      const size_t po = (size_t)(j0 + nt * 16 + ln16) * DH + kg * 8;
      bf16x8 pb0 = ldb8(&pP[po]);
      bf16x8 pb1 = ldb8(&pP[po + 32]);
      #pragma unroll
      for (int mt = 0; mt < 2; ++mt) {
        f32x4 g = {0.f, 0.f, 0.f, 0.f};
        g = MFMA16(va[mt][0], pb0, g);
        g = MFMA16(va[mt][1], pb1, g);
        #pragma unroll
        for (int jr = 0; jr < 4; ++jr)
          G[w][mt * 16 + kg * 4 + jr][nt * 16 + ln16] = g[jr];
      }
    }
    #pragma unroll
    for (int nt = 0; nt < 4; ++nt) {
      const size_t ko = (size_t)(ki0 + nt * 16 + ln16) * DH + kg * 8;
      bf16x8 kb0 = ldb8(&kP[ko]);
      bf16x8 kb1 = ldb8(&kP[ko + 32]);
      const float ak = (xmask[b * TT + ki0 + nt * 16 + ln16] - 1.f) * 10000.f;
      #pragma unroll
      for (int mt = 0; mt < 2; ++mt) {
        f32x4 dd = {0.f, 0.f, 0.f, 0.f};
        dd = MFMA16(qa[mt][0], kb0, dd);
        dd = MFMA16(qa[mt][1], kb1, dd);
        #pragma unroll
        for (int jr = 0; jr < 4; ++jr) {
          const int qrow = mt * 16 + kg * 4 + jr;
          const int u = nt * 16 + ln16 - qrow + 31;
          const float s = (dd[jr] + G[w][qrow][u]) * kScale + aq[mt][jr] + ak;
          rs[mt][jr] += __expf(s);
        }
      }
    }
  }
  #pragma unroll
  for (int mt = 0; mt < 2; ++mt)
    #pragma unroll
    for (int jr = 0; jr < 4; ++jr) {
      float v = rs[mt][jr];
      v += __shfl_xor(v, 1); v += __shfl_xor(v, 2);
      v += __shfl_xor(v, 4); v += __shfl_xor(v, 8);
      rs[mt][jr] = v;
    }
  if (ln16 == 0) {
    #pragma unroll
    for (int mt = 0; mt < 2; ++mt)
      #pragma unroll
      for (int jr = 0; jr < 4; ++jr)
        red[w][mt * 16 + kg * 4 + jr] = rs[mt][jr];
  }
  __syncthreads();
  if (tid < 32)
    ls[(size_t)bh * TT + qi0 + tid] = red[0][tid] + red[1][tid] + red[2][tid] + red[3][tid];
}

// ---------- Pass 2 (MFMA): partial ctx, qi split in 2; emits ctx2 bf16 ----------
// ctx2[b][t][part*512 + h*64 + d] ; flat grid 1024 (16 t-tiles x 2 parts x 32 bh)
__global__ __launch_bounds__(256)
void ctx_mfma(const u16* __restrict__ qu, const u16* __restrict__ qv,
              const u16* __restrict__ kk_, const u16* __restrict__ vv,
              const u16* __restrict__ pp, const float* __restrict__ xmask,
              const float* __restrict__ ls, u16* __restrict__ ctx2)
{
  const int tid = threadIdx.x;
  const int w = tid >> 6, lane = tid & 63;
  const int ln16 = lane & 15, kg = lane >> 4;
  const int bid = blockIdx.x;
  const int bh = (bid & 7) + 8 * ((bid >> 3) & 3);
  const int rest = bid >> 5;
  const int t0 = (rest & 15) * 64;
  const int part = rest >> 4;
  const int b = bh >> 3, h = bh & 7;
  const u16* quP = qu + (size_t)bh * TT * DH;
  const u16* qvP = qv + (size_t)bh * TT * DH;
  const u16* kP  = kk_ + (size_t)bh * TT * DH;
  const u16* vP  = vv + (size_t)bh * DH * TT;    // [d][t]
  const u16* pP  = pp + (size_t)h * 2048 * DH;
  const float* lsP = ls + (size_t)bh * TT;

  __shared__ float G[4][16][83];
  __shared__ __align__(16) u16 P[64][72];

  bf16x8 ka[4][2];
  #pragma unroll
  for (int nt = 0; nt < 4; ++nt)
    #pragma unroll
    for (int kc = 0; kc < 2; ++kc)
      ka[nt][kc] = ldb8(&kP[(size_t)(t0 + nt * 16 + ln16) * DH + kc * 32 + kg * 8]);
  float at4[4];
  #pragma unroll
  for (int nt = 0; nt < 4; ++nt)
    at4[nt] = (xmask[b * TT + t0 + nt * 16 + ln16] - 1.f) * 10000.f;

  f32x4 cacc[4] = {};
  for (int qc = part * 8; qc < part * 8 + 8; ++qc) {
    const int qw = qc * 64 + w * 16;
    const int j0 = t0 - qw + 1008;
    const size_t qo = (size_t)(qw + ln16) * DH + kg * 8;
    bf16x8 qa0 = ldb8(&quP[qo]), qa1 = ldb8(&quP[qo + 32]);
    bf16x8 va0 = ldb8(&qvP[qo]), va1 = ldb8(&qvP[qo + 32]);
    #pragma unroll
    for (int nt = 0; nt < 5; ++nt) {
      const size_t po = (size_t)(j0 + nt * 16 + ln16) * DH + kg * 8;
      bf16x8 pb0 = ldb8(&pP[po]), pb1 = ldb8(&pP[po + 32]);
      f32x4 g = {0.f, 0.f, 0.f, 0.f};
      g = MFMA16(va0, pb0, g);
      g = MFMA16(va1, pb1, g);
      #pragma unroll
      for (int jr = 0; jr < 4; ++jr)
        G[w][kg * 4 + jr][nt * 16 + ln16] = g[jr];
    }
    float linv[4], aqv[4];
    #pragma unroll
    for (int jr = 0; jr < 4; ++jr) {
      const int qi = qw + kg * 4 + jr;
      linv[jr] = 1.f / lsP[qi];
      aqv[jr] = (xmask[b * TT + qi] - 1.f) * 10000.f;
    }
    __syncthreads();
    #pragma unroll
    for (int nt = 0; nt < 4; ++nt) {
      f32x4 dd = {0.f, 0.f, 0.f, 0.f};
      dd = MFMA16(qa0, ka[nt][0], dd);
      dd = MFMA16(qa1, ka[nt][1], dd);
      unsigned lo = 0, hi = 0;
      #pragma unroll
      for (int jr = 0; jr < 4; ++jr) {
        const int qrow = kg * 4 + jr;
        const int u = nt * 16 + ln16 - qrow + 15;
        const float s = (dd[jr] + G[w][qrow][u]) * kScale + aqv[jr] + at4[nt];
        const float e = __expf(s) * linv[jr];
        const unsigned bb = f2b(e);
        if (jr == 0) lo = bb; else if (jr == 1) lo |= bb << 16;
        else if (jr == 2) hi = bb; else hi |= bb << 16;
      }
      *reinterpret_cast<uint2*>(&P[nt * 16 + ln16][w * 16 + kg * 4]) = make_uint2(lo, hi);
    }
    __syncthreads();
    const size_t vo = (size_t)(w * 16 + ln16) * TT + (qc & 15) * 64 + (qc >> 4) * 0;
    // v fragment: rows d = w*16+ln16, k = qi within this chunk
    const size_t vbase = (size_t)(w * 16 + ln16) * TT + qc * 64 + kg * 8;
    (void)vo;
    bf16x8 vf0 = ldb8(&vP[vbase]), vf1 = ldb8(&vP[vbase + 32]);
    #pragma unroll
    for (int nt = 0; nt < 4; ++nt) {
      bf16x8 pb0 = *reinterpret_cast<const bf16x8*>(&P[nt * 16 + ln16][kg * 8]);
      bf16x8 pb1 = *reinterpret_cast<const bf16x8*>(&P[nt * 16 + ln16][32 + kg * 8]);
      cacc[nt] = MFMA16(vf0, pb0, cacc[nt]);
      cacc[nt] = MFMA16(vf1, pb1, cacc[nt]);
    }
  }
  #pragma unroll
  for (int nt = 0; nt < 4; ++nt) {
    const int t = t0 + nt * 16 + ln16;
    ushort4 s4;
    s4.x = f2b(cacc[nt][0]); s4.y = f2b(cacc[nt][1]);
    s4.z = f2b(cacc[nt][2]); s4.w = f2b(cacc[nt][3]);
    *reinterpret_cast<ushort4*>(
      &ctx2[((size_t)b * TT + t) * 1024 + part * 512 + h * 64 + w * 16 + kg * 4]) = s4;
  }
}

// ---------- launch ----------
extern "C" void kernel_launch(void* const* d_in, const int* in_sizes, int n_in,
                              void* d_out, int out_size, void* d_ws, size_t ws_size,
                              hipStream_t stream)
{
  (void)in_sizes; (void)n_in; (void)out_size;
  const float* x     = (const float*)d_in[0];
  const float* pe    = (const float*)d_in[1];
  const float* xm    = (const float*)d_in[2];
  const float* gamma = (const float*)d_in[3];
  const float* beta  = (const float*)d_in[4];
  const float* Wq    = (const float*)d_in[5];
  const float* bq    = (const float*)d_in[6];
  const float* Wk    = (const float*)d_in[7];
  const float* bk    = (const float*)d_in[8];
  const float* Wv    = (const float*)d_in[9];
  const float* bv    = (const float*)d_in[10];
  const float* Wp    = (const float*)d_in[11];
  const float* ub    = (const float*)d_in[12];
  const float* vb    = (const float*)d_in[13];
  const float* Wo    = (const float*)d_in[14];
  const float* bo    = (const float*)d_in[15];

  // workspace layout (bytes); ctx2 overlays {xnT, posT, Wq/k/v/p-bf16} (all dead)
  char* ws = (char*)d_ws;
  u16* xnT  = (u16*)(ws + 0);          // [4][1024][512] bf16   (4 MB)
  u16* posT = (u16*)(ws + 4194304);    // [2048][512] bf16      (2 MB)
  u16* Wqb  = (u16*)(ws + 6291456);    // [512][512] bf16
  u16* Wkb  = (u16*)(ws + 6815744);
  u16* Wvb  = (u16*)(ws + 7340032);
  u16* Wpb  = (u16*)(ws + 7864320);
  u16* ctx2 = (u16*)(ws + 0);          // [4][1024][1024] bf16  (8 MB, overlay)
  u16* quB  = (u16*)(ws + 8388608);    // [32][1024][64] bf16
  u16* qvB  = (u16*)(ws + 12582912);
  u16* kB   = (u16*)(ws + 16777216);
  u16* vB   = (u16*)(ws + 20971520);   // [32][64][1024] bf16
  u16* pB   = (u16*)(ws + 25165824);   // [8][2048][64] bf16
  float* lsB = (float*)(ws + 27262976);// [32][1024] f32
  u16* Wo2  = (u16*)(ws + 27394048);   // [512][1024] bf16
  if (ws_size < 28442624) return;

  dim3 blk(256);
  const long XS = (long)TT * CB;       // xnT per-batch stride (elems)
  const long QS = (long)NH * TT * DH;  // q/k/v per-batch stride (elems)

  convert_bf16<<<dim3(128), blk, 0, stream>>>(Wq, Wqb, 32768);
  convert_bf16<<<dim3(128), blk, 0, stream>>>(Wk, Wkb, 32768);
  convert_bf16<<<dim3(128), blk, 0, stream>>>(Wv, Wvb, 32768);
  convert_bf16<<<dim3(128), blk, 0, stream>>>(Wp, Wpb, 32768);
  convert_wo2<<<dim3(256), blk, 0, stream>>>(Wo, Wo2);
  transpose_pe<<<dim3(32, 8), blk, 0, stream>>>(pe, posT);
  ln_kernel<<<dim3(32, 4), blk, 0, stream>>>(x, gamma, beta, xnT);

  gemm_mfma<512, 1, 1><<<dim3(16, 16, 4), blk, 0, stream>>>(
      Wqb, xnT, XS, QS, TT, bq, ub, vb, quB, qvB);
  gemm_mfma<512, 1, 0><<<dim3(16, 16, 4), blk, 0, stream>>>(
      Wkb, xnT, XS, QS, TT, bk, nullptr, nullptr, kB, nullptr);
  gemm_mfma<512, 2, 0><<<dim3(16, 16, 4), blk, 0, stream>>>(
      Wvb, xnT, XS, QS, TT, bv, nullptr, nullptr, vB, nullptr);
  gemm_mfma<512, 1, 0><<<dim3(32, 16, 1), blk, 0, stream>>>(
      Wpb, posT, 0, 0, 2048, nullptr, nullptr, nullptr, pB, nullptr);

  stats_mfma<<<dim3(1024), blk, 0, stream>>>(quB, qvB, kB, pB, xm, lsB);
  ctx_mfma<<<dim3(1024), blk, 0, stream>>>(quB, qvB, kB, vB, pB, xm, lsB, ctx2);

  gemm_mfma<1024, 0, 0><<<dim3(16, 16, 4), blk, 0, stream>>>(
      Wo2, ctx2, (long)TT * 1024, (long)CB * TT, TT, bo, nullptr, nullptr,
      (float*)d_out, nullptr);
}